// Round 4
// baseline (22905.429 us; speedup 1.0000x reference)
//
#include <hip/hip_runtime.h>

#define B_SZ 512
#define SEQ 96
#define PRED 48
#define TOT 144
#define CIN 7
#define DM 128
#define GDIM 384
#define KS 5

#define CSTR 132              // LDS row stride for activation buffers
#define ASUB (20*CSTR)        // floats per 20-row sub-buffer
#define WROW 136              // swizzled LDS weight row (128 + pad)
#define SWZ(o) ((o) + ((((o) >> 6)) << 2))   // bank swizzle: pad 4 every 64 floats

#define W_CONV (KS*DM*DM)            // 81920 per conv layer (layout [k][c][o])
#define OFF_WIT (3*W_CONV)           // WiT [c][384]
#define OFF_WHT (3*W_CONV + DM*GDIM) // WhT [c][384]
#define W_TOTAL (3*W_CONV + 2*DM*GDIM)

// ---- fused-kernel LDS layout (floats), 1 batch per block.
#define N_PREDH (PRED*8)                   // 384
#define L_ABUF  (N_PREDH)
#define N_ABUF  (2*ASUB)                   // 5280 (2 edge sub-buffers)
#define L_WBUF  (L_ABUF + N_ABUF)
#define N_WBUF  (16*GDIM)                  // 6144 (>= H overlay 288)
#define L_TOTAL (L_WBUF + N_WBUF)          // 11808 floats = 47.2 KB -> 2 blocks/CU

// Device-global scratch
__device__ float g_gxg[(size_t)B_SZ*TOT*GDIM];  // invariant gx cache, [b][p][384]
__device__ float g_gxe[B_SZ*12*GDIM];           // per-step edge gx, [b][12][384]
__device__ float g_wT[W_TOTAL];                 // transposed weights

// ---------------------------------------------------------------- prep
__global__ void prep_weights(const float* __restrict__ w1, const float* __restrict__ w2,
                             const float* __restrict__ w3, const float* __restrict__ Wi,
                             const float* __restrict__ Wh) {
    int tid = blockIdx.x*256 + threadIdx.x;
    if (tid < 3*W_CONV) {
        int l = tid / W_CONV, r = tid % W_CONV;
        int o = r & 127, c = (r >> 7) & 127, k = r >> 14;   // r = (k*128+c)*128+o
        const float* w = (l==0) ? w1 : ((l==1) ? w2 : w3);
        g_wT[tid] = w[o*(DM*KS) + c*KS + k];                 // src [o][c][k]
    } else if (tid < W_TOTAL) {
        int r = tid - 3*W_CONV;
        int m = r / (DM*GDIM), q = r % (DM*GDIM);
        int g = q % GDIM, c = q / GDIM;                      // dst [c][g]
        const float* W = (m==0) ? Wi : Wh;
        g_wT[tid] = W[g*DM + c];                             // src [g][c]
    }
}

// ---------------------------------------------------------------- fma helper
template<int NJ>
__device__ __forceinline__ void fma8(float (&acc)[NJ][8], int j, float a,
                                     const float4& wA, const float4& wB) {
    acc[j][0] = fmaf(a, wA.x, acc[j][0]);
    acc[j][1] = fmaf(a, wA.y, acc[j][1]);
    acc[j][2] = fmaf(a, wA.z, acc[j][2]);
    acc[j][3] = fmaf(a, wA.w, acc[j][3]);
    acc[j][4] = fmaf(a, wB.x, acc[j][4]);
    acc[j][5] = fmaf(a, wB.y, acc[j][5]);
    acc[j][6] = fmaf(a, wB.z, acc[j][6]);
    acc[j][7] = fmaf(a, wB.w, acc[j][7]);
}

// stage 8 channels of conv weights (swizzled) into wbuf — 256-thread version
__device__ __forceinline__ void stage_conv_chunk(float* __restrict__ wbuf,
                                                 const float* __restrict__ wT,
                                                 int cc, int tid) {
    const int cj = tid >> 5, oo = (tid & 31) * 4;
    #pragma unroll
    for (int k = 0; k < KS; ++k)
        *(float4*)(wbuf + (k*8 + cj)*WROW + SWZ(oo)) =
            *(const float4*)(wT + (k*DM + cc*8 + cj)*DM + oo);
}

// stage 8 channels of conv weights (swizzled) into wbuf — 512-thread version
__device__ __forceinline__ void stage_conv_chunk512(float* __restrict__ wbuf,
                                                    const float* __restrict__ wT,
                                                    int cc, int tid) {
    const int cj = tid >> 6, oo = (tid & 63) * 2;   // float2 within one 64-block: no SWZ straddle
    #pragma unroll
    for (int k = 0; k < KS; ++k)
        *(float2*)(wbuf + (k*8 + cj)*WROW + SWZ(oo)) =
            *(const float2*)(wT + (k*DM + cc*8 + cj)*DM + oo);
}

// Chunked in-place conv layer (init kernel, 256 threads).
template<int NJ>
__device__ __forceinline__ void conv_layer_chunked(float* __restrict__ buf,
                                                   float* __restrict__ wbuf,
                                                   const float* __restrict__ wT,
                                                   const float* __restrict__ bias,
                                                   int nrow, int winO, int tid) {
    const int og = tid & 15, ttg = tid >> 4;
    const int o0 = og*8, so0 = SWZ(o0), r0 = ttg*NJ;
    const bool act = (r0 < nrow);
    float acc[NJ][8];
    #pragma unroll
    for (int u = 0; u < 8; ++u) {
        float bv = bias[o0+u];
        #pragma unroll
        for (int j = 0; j < NJ; ++j) acc[j][u] = bv;
    }
    for (int cc = 0; cc < DM/8; ++cc) {
        __syncthreads();
        stage_conv_chunk(wbuf, wT, cc, tid);
        __syncthreads();
        if (act) {
            const int c0 = cc*8;
            #pragma unroll
            for (int cj = 0; cj < 8; cj += 2) {
                float2 a2[NJ+4];
                #pragma unroll
                for (int m = 0; m < NJ+4; ++m)
                    a2[m] = *(const float2*)(buf + (r0+m)*CSTR + c0 + cj);
                #pragma unroll
                for (int k = 0; k < KS; ++k) {
                    const float4 wA0 = *(const float4*)(wbuf + (k*8+cj)*WROW + so0);
                    const float4 wB0 = *(const float4*)(wbuf + (k*8+cj)*WROW + so0 + 4);
                    const float4 wA1 = *(const float4*)(wbuf + (k*8+cj+1)*WROW + so0);
                    const float4 wB1 = *(const float4*)(wbuf + (k*8+cj+1)*WROW + so0 + 4);
                    #pragma unroll
                    for (int j = 0; j < NJ; ++j) {
                        fma8(acc, j, a2[j+k].x, wA0, wB0);
                        fma8(acc, j, a2[j+k].y, wA1, wB1);
                    }
                }
            }
        }
    }
    __syncthreads();
    if (act) {
        #pragma unroll
        for (int j = 0; j < NJ; ++j) {
            int q = r0 + j, w = winO + q;
            bool valid = (w >= 0) && (w < SEQ);
            #pragma unroll
            for (int u = 0; u < 8; ++u)
                buf[q*CSTR + o0+u] = valid ? fmaxf(acc[j][u], 0.f) : 0.f;
        }
    }
    __syncthreads();
}

// ------------------------------------------------------------- init kernel
// Step 0's full conv cascade; stores invariant gx rows w in [6,90) to g_gxg[b][w].
__launch_bounds__(256, 3)
__global__ void init_kernel(const float* __restrict__ x_enc,
                            const int* __restrict__ y_mark,
                            const float* __restrict__ hour_e, const float* __restrict__ wk_e,
                            const float* __restrict__ day_e, const float* __restrict__ mon_e,
                            const float* __restrict__ W_val, const float* __restrict__ b_val,
                            const float* __restrict__ b1, const float* __restrict__ b2,
                            const float* __restrict__ b3, const float* __restrict__ gbi) {
    __shared__ float buf[60*CSTR];
    __shared__ float wbuf[KS*8*WROW];
    const int tid = threadIdx.x;
    const int b = blockIdx.x;
    const int cs = blockIdx.y * 48;

    for (int e = tid; e < 60*DM; e += 256) {
        int q = e >> 7, d = e & 127;
        int w = cs - 6 + q;
        float v = 0.f;
        if (w >= 0 && w < SEQ) {
            const float* xr = x_enc + (b*SEQ + w)*CIN;
            v = b_val[d];
            #pragma unroll
            for (int c = 0; c < CIN; ++c) v = fmaf(xr[c], W_val[d*CIN + c], v);
            const int* ym = y_mark + (b*TOT + w)*4;
            v += hour_e[ym[0]*DM + d] + wk_e[ym[1]*DM + d]
               + day_e[ym[2]*DM + d] + mon_e[ym[3]*DM + d];
        }
        buf[q*CSTR + d] = v;
    }
    conv_layer_chunked<4>(buf, wbuf, g_wT,            b1, 56, cs - 4, tid);
    conv_layer_chunked<4>(buf, wbuf, g_wT + W_CONV,   b2, 52, cs - 2, tid);
    conv_layer_chunked<3>(buf, wbuf, g_wT + 2*W_CONV, b3, 48, cs,     tid);

    const int og = tid & 15, ttg = tid >> 4;
    const int g0 = og*24, r0 = ttg*3;
    const float* WiT = g_wT + OFF_WIT;
    float ga[3][24];
    #pragma unroll
    for (int e = 0; e < 24; ++e) {
        float bv = gbi[g0+e];
        #pragma unroll
        for (int j = 0; j < 3; ++j) ga[j][e] = bv;
    }
    for (int cc = 0; cc < DM/8; ++cc) {
        __syncthreads();
        #pragma unroll
        for (int s = 0; s < 3; ++s)
            ((float4*)wbuf)[s*256 + tid] = ((const float4*)(WiT + cc*8*GDIM))[s*256 + tid];
        __syncthreads();
        const int c0 = cc*8;
        #pragma unroll
        for (int cj = 0; cj < 8; cj += 2) {
            float2 a2[3];
            #pragma unroll
            for (int m = 0; m < 3; ++m)
                a2[m] = *(const float2*)(buf + (r0+m)*CSTR + c0 + cj);
            float4 w4[6];
            #pragma unroll
            for (int q = 0; q < 6; ++q)
                w4[q] = *(const float4*)(wbuf + cj*GDIM + g0 + q*4);
            const float* wv = (const float*)w4;
            #pragma unroll
            for (int j = 0; j < 3; ++j)
                #pragma unroll
                for (int e = 0; e < 24; ++e)
                    ga[j][e] = fmaf(a2[j].x, wv[e], ga[j][e]);
            #pragma unroll
            for (int q = 0; q < 6; ++q)
                w4[q] = *(const float4*)(wbuf + (cj+1)*GDIM + g0 + q*4);
            #pragma unroll
            for (int j = 0; j < 3; ++j)
                #pragma unroll
                for (int e = 0; e < 24; ++e)
                    ga[j][e] = fmaf(a2[j].y, wv[e], ga[j][e]);
        }
    }
    #pragma unroll
    for (int j = 0; j < 3; ++j) {
        int w = cs + r0 + j;
        if (w >= 6 && w < 90) {
            float* gxo = g_gxg + ((size_t)b*TOT + w)*GDIM + g0;
            #pragma unroll
            for (int q = 0; q < 6; ++q)
                *(float4*)(gxo + q*4) = *(const float4*)&ga[j][q*4];
        }
    }
}

// ------------------------------------------------------------- fused step layer
// 512 threads, one batch, 2 edge sub-buffers. NJ=1: ttg in [0,32) covers 2R rows.
__device__ __forceinline__ void mlayer512(float* __restrict__ abuf, float* __restrict__ wbuf,
                                          const float* __restrict__ wT,
                                          const float* __restrict__ bias,
                                          int R, int off, int tid) {
    const int og = tid & 15, ttg = tid >> 4;     // og 0..15, ttg 0..31
    const int o0 = og*8, so0 = SWZ(o0);
    const bool act = (ttg < 2*R);
    int s = 0, r0 = 0;
    if (act) { s = ttg / R; r0 = ttg - s*R; }
    float* in = abuf + s*ASUB;
    float acc[1][8];
    #pragma unroll
    for (int u = 0; u < 8; ++u) acc[0][u] = bias[o0+u];
    for (int cc = 0; cc < DM/8; ++cc) {
        __syncthreads();
        stage_conv_chunk512(wbuf, wT, cc, tid);
        __syncthreads();
        if (act) {
            const int c0 = cc*8;
            #pragma unroll
            for (int cj = 0; cj < 8; cj += 2) {
                float2 a2[5];
                #pragma unroll
                for (int m = 0; m < 5; ++m)
                    a2[m] = *(const float2*)(in + (r0+m)*CSTR + c0 + cj);
                #pragma unroll
                for (int k = 0; k < KS; ++k) {
                    const float4 wA0 = *(const float4*)(wbuf + (k*8+cj)*WROW + so0);
                    const float4 wB0 = *(const float4*)(wbuf + (k*8+cj)*WROW + so0 + 4);
                    const float4 wA1 = *(const float4*)(wbuf + (k*8+cj+1)*WROW + so0);
                    const float4 wB1 = *(const float4*)(wbuf + (k*8+cj+1)*WROW + so0 + 4);
                    fma8(acc, 0, a2[k].x, wA0, wB0);
                    fma8(acc, 0, a2[k].y, wA1, wB1);
                }
            }
        }
    }
    __syncthreads();
    if (act) {
        const int wb = s ? 83 : -6;
        int w = wb + off + r0;
        bool valid = (w >= 0) && (w < SEQ);
        #pragma unroll
        for (int u = 0; u < 8; ++u)
            in[r0*CSTR + o0+u] = valid ? fmaxf(acc[0][u], 0.f) : 0.f;
    }
    __syncthreads();
}

// ------------------------------------------------------------- fused kernel
// grid 512 x 512 threads (2 blocks/CU). Block owns ONE batch for the entire
// 48-step loop: phase A (edge conv + gx) then phase B (GRU). Single launch.
// NOTE: min-waves-per-EU = 2 (NOT 4): the GRU holds 96 floats of Wh slices
// per thread; a 64-VGPR cap spills them (measured r3: FETCH_SIZE doubled).
__launch_bounds__(512, 2)
__global__ void fused_loop(const float* __restrict__ x_enc,
                           const int* __restrict__ y_mark,
                           const float* __restrict__ hour_e, const float* __restrict__ wk_e,
                           const float* __restrict__ day_e, const float* __restrict__ mon_e,
                           const float* __restrict__ W_val, const float* __restrict__ b_val,
                           const float* __restrict__ b1, const float* __restrict__ b2,
                           const float* __restrict__ b3, const float* __restrict__ gbi,
                           const float* __restrict__ gbh,
                           const float* __restrict__ fc_w, const float* __restrict__ fc_b,
                           float* __restrict__ out) {
    __shared__ __align__(16) float lds[L_TOTAL];   // 47.2 KB -> 2 blocks/CU
    float* const predH = lds;                      // [PRED][8]
    float* const wbuf  = lds + L_WBUF;             // phase A staging
    float* const Hbuf  = wbuf;                     // phase B overlay: [2][144] (36-padded)
    float* const ab    = lds + L_ABUF;             // 2 sub-buffers

    const int tid = threadIdx.x;
    const int b   = blockIdx.x;

    // GRU thread roles: unit j = tid>>2, c-slice s = tid&3 (4 adjacent lanes
    // per unit -> slice combine is a 2-step shfl_xor, no LDS, no barrier).
    const int gj4 = tid >> 2, s4 = tid & 3;

    const float* gxg_b = g_gxg + (size_t)b*TOT*GDIM;
    const float* gxe_b = g_gxe + (size_t)b*12*GDIM;

    #pragma unroll 1
    for (int i = 0; i < PRED; ++i) {
        __syncthreads();   // predH from iter i-1 visible; LDS reuse safe

        // ---- phase A: embedding (2 subs x 20 rows x 128)
        for (int e = tid; e < 2*20*DM; e += 512) {
            int s = e / (20*DM);
            int rem = e - s*(20*DM);
            int q = rem >> 7, d = rem & 127;
            int w = (s ? 83 : -6) + q;
            float v = 0.f;
            if (w >= 0 && w < SEQ) {
                int p = i + w;
                v = b_val[d];
                if (p < SEQ) {
                    const float* xr = x_enc + (b*SEQ + p)*CIN;
                    #pragma unroll
                    for (int c = 0; c < CIN; ++c) v = fmaf(xr[c], W_val[d*CIN + c], v);
                } else {
                    const float* xr = predH + (p - SEQ)*8;
                    #pragma unroll
                    for (int c = 0; c < CIN; ++c) v = fmaf(xr[c], W_val[d*CIN + c], v);
                }
                const int* ym = y_mark + (b*TOT + p)*4;
                v += hour_e[ym[0]*DM + d] + wk_e[ym[1]*DM + d]
                   + day_e[ym[2]*DM + d] + mon_e[ym[3]*DM + d];
            }
            ab[s*ASUB + q*CSTR + d] = v;
        }
        // (mlayer's leading __syncthreads orders embedding writes vs staging)
        mlayer512(ab, wbuf, g_wT,            b1, 16, 2, tid);  // c1: 32 rows
        mlayer512(ab, wbuf, g_wT + W_CONV,   b2, 12, 4, tid);  // c2: 24 rows
        mlayer512(ab, wbuf, g_wT + 2*W_CONV, b3,  8, 6, tid);  // c3: 16 rows

        // ---- gx: 16 c3 rows; thread tile = 1 row x 12 g
        {
            const int row = tid >> 5;                // 0..15
            const int g0 = (tid & 31) * 12;
            const int ssub = row >> 3;
            const int r = row & 7;
            const float* a0p = ab + ssub*ASUB + r*CSTR;
            const float* WiT = g_wT + OFF_WIT;
            float ga[12];
            #pragma unroll
            for (int e = 0; e < 12; ++e) ga[e] = gbi[g0+e];
            for (int cc = 0; cc < 8; ++cc) {
                __syncthreads();
                for (int x = tid; x < 16*GDIM/4; x += 512)
                    ((float4*)wbuf)[x] = ((const float4*)(WiT + cc*16*GDIM))[x];
                __syncthreads();
                #pragma unroll
                for (int c = 0; c < 16; ++c) {
                    float av = a0p[cc*16 + c];
                    const float* wr = wbuf + c*GDIM + g0;
                    #pragma unroll
                    for (int q4 = 0; q4 < 3; ++q4) {
                        float4 w4 = *(const float4*)(wr + q4*4);
                        ga[q4*4+0] = fmaf(av, w4.x, ga[q4*4+0]);
                        ga[q4*4+1] = fmaf(av, w4.y, ga[q4*4+1]);
                        ga[q4*4+2] = fmaf(av, w4.z, ga[q4*4+2]);
                        ga[q4*4+3] = fmaf(av, w4.w, ga[q4*4+3]);
                    }
                }
            }
            const int wb = ssub ? 83 : -6;
            int w = wb + 6 + r;
            float* dst = nullptr;
            if (ssub == 0) {
                if (w < 6) dst = g_gxe + ((size_t)b*12 + w)*GDIM + g0;
            } else {
                if (w == 89)      dst = g_gxg + ((size_t)b*TOT + (i + 89))*GDIM + g0;
                else if (w < SEQ) dst = g_gxe + ((size_t)b*12 + (w - 84))*GDIM + g0;
            }
            if (dst) {
                *(float4*)(dst)     = *(const float4*)&ga[0];
                *(float4*)(dst + 4) = *(const float4*)&ga[4];
                *(float4*)(dst + 8) = *(const float4*)&ga[8];
            }
        }

        __syncthreads();   // wbuf reads done (H overlay safe); gx stores visible

        // ---- phase B: GRU, shuffle-reduce form. ONE barrier per t-step.
        // Wh slice for (unit gj4, c in [32*s4, 32*s4+32)), all 3 gates.
        float whr[32], whz[32], whn[32];
        {
            const float* Wp = g_wT + OFF_WHT + (size_t)(32*s4)*GDIM + gj4;
            #pragma unroll
            for (int c = 0; c < 32; ++c) {
                whr[c] = Wp[c*GDIM];
                whz[c] = Wp[c*GDIM + DM];
                whn[c] = Wp[c*GDIM + 2*DM];
            }
        }
        const float bhr = gbh[gj4], bhz = gbh[DM + gj4], bhn = gbh[2*DM + gj4];
        if (tid < 2*144) Hbuf[tid] = 0.f;          // zero both 36-padded H buffers

        auto gp = [&](int t) -> const float* {
            return (t < 6)  ? (gxe_b + t*GDIM)
                 : (t < 90) ? (gxg_b + (size_t)(i + t)*GDIM)
                            : (gxe_b + (t - 84)*GDIM);
        };

        float gxr, gxz, gxn;
        {
            const float* g0p = gp(0);
            gxr = g0p[gj4]; gxz = g0p[DM + gj4]; gxn = g0p[2*DM + gj4];
        }
        float hold = 0.f;                          // unit gj4's h(t-1), in-register
        __syncthreads();

        for (int t = 0; t < SEQ; ++t) {
            // prefetch t+1's gx first: its latency hides under the dots below
            float nr = 0.f, nz = 0.f, nn = 0.f;
            if (t + 1 < SEQ) {
                const float* gq = gp(t + 1);
                nr = gq[gj4]; nz = gq[DM + gj4]; nn = gq[2*DM + gj4];
            }
            // slice dots: 3 gates x 32 MACs. 36-pad -> the 4 slices' float4
            // reads land on disjoint banks (16-lane broadcast per address).
            const float* Hc = Hbuf + (t & 1)*144 + 36*s4;
            float ar = 0.f, az = 0.f, an = 0.f;
            #pragma unroll
            for (int c = 0; c < 32; c += 4) {
                float4 h4 = *(const float4*)(Hc + c);
                ar = fmaf(h4.x, whr[c],   ar); az = fmaf(h4.x, whz[c],   az); an = fmaf(h4.x, whn[c],   an);
                ar = fmaf(h4.y, whr[c+1], ar); az = fmaf(h4.y, whz[c+1], az); an = fmaf(h4.y, whn[c+1], an);
                ar = fmaf(h4.z, whr[c+2], ar); az = fmaf(h4.z, whz[c+2], az); an = fmaf(h4.z, whn[c+2], an);
                ar = fmaf(h4.w, whr[c+3], ar); az = fmaf(h4.w, whz[c+3], az); an = fmaf(h4.w, whn[c+3], an);
            }
            // combine across the 4 slice lanes (stays within lane group)
            ar += __shfl_xor(ar, 1); ar += __shfl_xor(ar, 2);
            az += __shfl_xor(az, 1); az += __shfl_xor(az, 2);
            an += __shfl_xor(an, 1); an += __shfl_xor(an, 2);
            // gate math, redundant in all 4 lanes
            float r = 1.f/(1.f + __expf(-(gxr + bhr + ar)));
            float z = 1.f/(1.f + __expf(-(gxz + bhz + az)));
            float xn = gxn + r*(bhn + an);
            float e2 = __expf(2.f*xn);
            float n = 1.f - 2.f/(e2 + 1.f);        // tanh(xn)
            float h = (1.f - z)*n + z*hold;
            hold = h;
            if (s4 == 0)
                Hbuf[((t + 1) & 1)*144 + 36*(gj4 >> 5) + (gj4 & 31)] = h;
            gxr = nr; gxz = nz; gxn = nn;
            __syncthreads();                       // h visible for next t's dots
        }

        // ---- pred = h @ fc_w^T + fc_b (SEQ even -> final state in Hbuf[0])
        if (tid < CIN) {
            int o = tid;
            float p = fc_b[o];
            #pragma unroll
            for (int d = 0; d < DM; ++d)
                p = fmaf(fc_w[o*DM + d], Hbuf[36*(d >> 5) + (d & 31)], p);
            out[(b*PRED + i)*CIN + o] = p;
            predH[i*8 + o] = p;
        }
    }
}

// ---------------------------------------------------------------- launch
extern "C" void kernel_launch(void* const* d_in, const int* in_sizes, int n_in,
                              void* d_out, int out_size, void* d_ws, size_t ws_size,
                              hipStream_t stream) {
    const float* x_enc  = (const float*)d_in[0];
    const int*   y_mark = (const int*)d_in[2];
    const float* hour_e = (const float*)d_in[3];
    const float* wk_e   = (const float*)d_in[4];
    const float* day_e  = (const float*)d_in[5];
    const float* mon_e  = (const float*)d_in[6];
    const float* W_val  = (const float*)d_in[7];
    const float* b_val  = (const float*)d_in[8];
    const float* c1w    = (const float*)d_in[9];
    const float* c1b    = (const float*)d_in[10];
    const float* c2w    = (const float*)d_in[11];
    const float* c2b    = (const float*)d_in[12];
    const float* c3w    = (const float*)d_in[13];
    const float* c3b    = (const float*)d_in[14];
    const float* Wi     = (const float*)d_in[15];
    const float* Wh     = (const float*)d_in[16];
    const float* gbi    = (const float*)d_in[17];
    const float* gbh    = (const float*)d_in[18];
    const float* fcw    = (const float*)d_in[19];
    const float* fcb    = (const float*)d_in[20];
    float* out = (float*)d_out;

    prep_weights<<<(W_TOTAL + 255)/256, 256, 0, stream>>>(c1w, c2w, c3w, Wi, Wh);

    init_kernel<<<dim3(B_SZ, 2), 256, 0, stream>>>(x_enc, y_mark,
        hour_e, wk_e, day_e, mon_e, W_val, b_val, c1b, c2b, c3b, gbi);

    fused_loop<<<B_SZ, 512, 0, stream>>>(x_enc, y_mark,
        hour_e, wk_e, day_e, mon_e, W_val, b_val, c1b, c2b, c3b,
        gbi, gbh, fcw, fcb, out);
}

// Round 6
// 12808.839 us; speedup vs baseline: 1.7883x; 1.7883x over previous
//
#include <hip/hip_runtime.h>

#define B_SZ 512
#define SEQ 96
#define PRED 48
#define TOT 144
#define CIN 7
#define DM 128
#define GDIM 384
#define KS 5

#define CSTR 132              // LDS row stride for activation buffers
#define ASUB (20*CSTR)        // floats per 20-row sub-buffer
#define WROW 136              // swizzled LDS weight row (128 + pad)
#define SWZ(o) ((o) + ((((o) >> 6)) << 2))   // bank swizzle: pad 4 every 64 floats

#define W_CONV (KS*DM*DM)            // 81920 per conv layer (layout [k][c][o])
#define OFF_WIT (3*W_CONV)           // WiT [c][384]
#define OFF_WHT (3*W_CONV + DM*GDIM) // WhT [c][384]
#define W_TOTAL (3*W_CONV + 2*DM*GDIM)

#define NBB 2                 // batches per gru block

// Device-global scratch
__device__ float g_gxg[(size_t)B_SZ*TOT*GDIM];  // invariant gx cache, [b][p][384]
__device__ float g_gxe[B_SZ*12*GDIM];           // per-step edge gx, [b][12][384]
__device__ float g_wT[W_TOTAL];                 // transposed weights

// ---------------------------------------------------------------- prep
__global__ void prep_weights(const float* __restrict__ w1, const float* __restrict__ w2,
                             const float* __restrict__ w3, const float* __restrict__ Wi,
                             const float* __restrict__ Wh) {
    int tid = blockIdx.x*256 + threadIdx.x;
    if (tid < 3*W_CONV) {
        int l = tid / W_CONV, r = tid % W_CONV;
        int o = r & 127, c = (r >> 7) & 127, k = r >> 14;   // r = (k*128+c)*128+o
        const float* w = (l==0) ? w1 : ((l==1) ? w2 : w3);
        g_wT[tid] = w[o*(DM*KS) + c*KS + k];                 // src [o][c][k]
    } else if (tid < W_TOTAL) {
        int r = tid - 3*W_CONV;
        int m = r / (DM*GDIM), q = r % (DM*GDIM);
        int g = q % GDIM, c = q / GDIM;                      // dst [c][g]
        const float* W = (m==0) ? Wi : Wh;
        g_wT[tid] = W[g*DM + c];                             // src [g][c]
    }
}

// ---------------------------------------------------------------- fma helper
template<int NJ>
__device__ __forceinline__ void fma8(float (&acc)[NJ][8], int j, float a,
                                     const float4& wA, const float4& wB) {
    acc[j][0] = fmaf(a, wA.x, acc[j][0]);
    acc[j][1] = fmaf(a, wA.y, acc[j][1]);
    acc[j][2] = fmaf(a, wA.z, acc[j][2]);
    acc[j][3] = fmaf(a, wA.w, acc[j][3]);
    acc[j][4] = fmaf(a, wB.x, acc[j][4]);
    acc[j][5] = fmaf(a, wB.y, acc[j][5]);
    acc[j][6] = fmaf(a, wB.z, acc[j][6]);
    acc[j][7] = fmaf(a, wB.w, acc[j][7]);
}

// stage 8 channels of conv weights (swizzled) into wbuf — 256-thread version
__device__ __forceinline__ void stage_conv_chunk(float* __restrict__ wbuf,
                                                 const float* __restrict__ wT,
                                                 int cc, int tid) {
    const int cj = tid >> 5, oo = (tid & 31) * 4;
    #pragma unroll
    for (int k = 0; k < KS; ++k)
        *(float4*)(wbuf + (k*8 + cj)*WROW + SWZ(oo)) =
            *(const float4*)(wT + (k*DM + cc*8 + cj)*DM + oo);
}

// Chunked in-place conv layer (init kernel, 256 threads).
template<int NJ>
__device__ __forceinline__ void conv_layer_chunked(float* __restrict__ buf,
                                                   float* __restrict__ wbuf,
                                                   const float* __restrict__ wT,
                                                   const float* __restrict__ bias,
                                                   int nrow, int winO, int tid) {
    const int og = tid & 15, ttg = tid >> 4;
    const int o0 = og*8, so0 = SWZ(o0), r0 = ttg*NJ;
    const bool act = (r0 < nrow);
    float acc[NJ][8];
    #pragma unroll
    for (int u = 0; u < 8; ++u) {
        float bv = bias[o0+u];
        #pragma unroll
        for (int j = 0; j < NJ; ++j) acc[j][u] = bv;
    }
    for (int cc = 0; cc < DM/8; ++cc) {
        __syncthreads();
        stage_conv_chunk(wbuf, wT, cc, tid);
        __syncthreads();
        if (act) {
            const int c0 = cc*8;
            #pragma unroll
            for (int cj = 0; cj < 8; cj += 2) {
                float2 a2[NJ+4];
                #pragma unroll
                for (int m = 0; m < NJ+4; ++m)
                    a2[m] = *(const float2*)(buf + (r0+m)*CSTR + c0 + cj);
                #pragma unroll
                for (int k = 0; k < KS; ++k) {
                    const float4 wA0 = *(const float4*)(wbuf + (k*8+cj)*WROW + so0);
                    const float4 wB0 = *(const float4*)(wbuf + (k*8+cj)*WROW + so0 + 4);
                    const float4 wA1 = *(const float4*)(wbuf + (k*8+cj+1)*WROW + so0);
                    const float4 wB1 = *(const float4*)(wbuf + (k*8+cj+1)*WROW + so0 + 4);
                    #pragma unroll
                    for (int j = 0; j < NJ; ++j) {
                        fma8(acc, j, a2[j+k].x, wA0, wB0);
                        fma8(acc, j, a2[j+k].y, wA1, wB1);
                    }
                }
            }
        }
    }
    __syncthreads();
    if (act) {
        #pragma unroll
        for (int j = 0; j < NJ; ++j) {
            int q = r0 + j, w = winO + q;
            bool valid = (w >= 0) && (w < SEQ);
            #pragma unroll
            for (int u = 0; u < 8; ++u)
                buf[q*CSTR + o0+u] = valid ? fmaxf(acc[j][u], 0.f) : 0.f;
        }
    }
    __syncthreads();
}

// ------------------------------------------------------------- init kernel
// Step 0's full conv cascade; stores invariant gx rows w in [6,90) to g_gxg[b][w].
__launch_bounds__(256, 3)
__global__ void init_kernel(const float* __restrict__ x_enc,
                            const int* __restrict__ y_mark,
                            const float* __restrict__ hour_e, const float* __restrict__ wk_e,
                            const float* __restrict__ day_e, const float* __restrict__ mon_e,
                            const float* __restrict__ W_val, const float* __restrict__ b_val,
                            const float* __restrict__ b1, const float* __restrict__ b2,
                            const float* __restrict__ b3, const float* __restrict__ gbi) {
    __shared__ float buf[60*CSTR];
    __shared__ float wbuf[KS*8*WROW];
    const int tid = threadIdx.x;
    const int b = blockIdx.x;
    const int cs = blockIdx.y * 48;

    for (int e = tid; e < 60*DM; e += 256) {
        int q = e >> 7, d = e & 127;
        int w = cs - 6 + q;
        float v = 0.f;
        if (w >= 0 && w < SEQ) {
            const float* xr = x_enc + (b*SEQ + w)*CIN;
            v = b_val[d];
            #pragma unroll
            for (int c = 0; c < CIN; ++c) v = fmaf(xr[c], W_val[d*CIN + c], v);
            const int* ym = y_mark + (b*TOT + w)*4;
            v += hour_e[ym[0]*DM + d] + wk_e[ym[1]*DM + d]
               + day_e[ym[2]*DM + d] + mon_e[ym[3]*DM + d];
        }
        buf[q*CSTR + d] = v;
    }
    conv_layer_chunked<4>(buf, wbuf, g_wT,            b1, 56, cs - 4, tid);
    conv_layer_chunked<4>(buf, wbuf, g_wT + W_CONV,   b2, 52, cs - 2, tid);
    conv_layer_chunked<3>(buf, wbuf, g_wT + 2*W_CONV, b3, 48, cs,     tid);

    const int og = tid & 15, ttg = tid >> 4;
    const int g0 = og*24, r0 = ttg*3;
    const float* WiT = g_wT + OFF_WIT;
    float ga[3][24];
    #pragma unroll
    for (int e = 0; e < 24; ++e) {
        float bv = gbi[g0+e];
        #pragma unroll
        for (int j = 0; j < 3; ++j) ga[j][e] = bv;
    }
    for (int cc = 0; cc < DM/8; ++cc) {
        __syncthreads();
        #pragma unroll
        for (int s = 0; s < 3; ++s)
            ((float4*)wbuf)[s*256 + tid] = ((const float4*)(WiT + cc*8*GDIM))[s*256 + tid];
        __syncthreads();
        const int c0 = cc*8;
        #pragma unroll
        for (int cj = 0; cj < 8; cj += 2) {
            float2 a2[3];
            #pragma unroll
            for (int m = 0; m < 3; ++m)
                a2[m] = *(const float2*)(buf + (r0+m)*CSTR + c0 + cj);
            float4 w4[6];
            #pragma unroll
            for (int q = 0; q < 6; ++q)
                w4[q] = *(const float4*)(wbuf + cj*GDIM + g0 + q*4);
            const float* wv = (const float*)w4;
            #pragma unroll
            for (int j = 0; j < 3; ++j)
                #pragma unroll
                for (int e = 0; e < 24; ++e)
                    ga[j][e] = fmaf(a2[j].x, wv[e], ga[j][e]);
            #pragma unroll
            for (int q = 0; q < 6; ++q)
                w4[q] = *(const float4*)(wbuf + (cj+1)*GDIM + g0 + q*4);
            #pragma unroll
            for (int j = 0; j < 3; ++j)
                #pragma unroll
                for (int e = 0; e < 24; ++e)
                    ga[j][e] = fmaf(a2[j].y, wv[e], ga[j][e]);
        }
    }
    #pragma unroll
    for (int j = 0; j < 3; ++j) {
        int w = cs + r0 + j;
        if (w >= 6 && w < 90) {
            float* gxo = g_gxg + ((size_t)b*TOT + w)*GDIM + g0;
            #pragma unroll
            for (int q = 0; q < 6; ++q)
                *(float4*)(gxo + q*4) = *(const float4*)&ga[j][q*4];
        }
    }
}

// ------------------------------------------------------------- step layer
// 256 threads, 2 sub-buffers (left/right edge of one batch). R rows/sub.
template<int NJ>
__device__ __forceinline__ void mlayer(float* __restrict__ abuf, float* __restrict__ wbuf,
                                       const float* __restrict__ wT,
                                       const float* __restrict__ bias,
                                       int R, int off, int tid) {
    const int og = tid & 15, ttg = tid >> 4;     // og 0..15, ttg 0..15
    const int o0 = og*8, so0 = SWZ(o0);
    const int m0 = ttg * NJ;
    const bool act = (m0 < 2*R);
    int s = 0, r0 = 0;
    if (act) { s = m0 / R; r0 = m0 - s*R; }      // NJ divides R -> rows don't span subs
    float* in = abuf + s*ASUB;
    float acc[NJ][8];
    #pragma unroll
    for (int u = 0; u < 8; ++u) {
        float bv = bias[o0+u];
        #pragma unroll
        for (int j = 0; j < NJ; ++j) acc[j][u] = bv;
    }
    for (int cc = 0; cc < DM/8; ++cc) {
        __syncthreads();
        stage_conv_chunk(wbuf, wT, cc, tid);
        __syncthreads();
        if (act) {
            const int c0 = cc*8;
            #pragma unroll
            for (int cj = 0; cj < 8; cj += 2) {
                float2 a2[NJ+4];
                #pragma unroll
                for (int m = 0; m < NJ+4; ++m)
                    a2[m] = *(const float2*)(in + (r0+m)*CSTR + c0 + cj);
                #pragma unroll
                for (int k = 0; k < KS; ++k) {
                    const float4 wA0 = *(const float4*)(wbuf + (k*8+cj)*WROW + so0);
                    const float4 wB0 = *(const float4*)(wbuf + (k*8+cj)*WROW + so0 + 4);
                    const float4 wA1 = *(const float4*)(wbuf + (k*8+cj+1)*WROW + so0);
                    const float4 wB1 = *(const float4*)(wbuf + (k*8+cj+1)*WROW + so0 + 4);
                    #pragma unroll
                    for (int j = 0; j < NJ; ++j) {
                        fma8(acc, j, a2[j+k].x, wA0, wB0);
                        fma8(acc, j, a2[j+k].y, wA1, wB1);
                    }
                }
            }
        }
    }
    __syncthreads();
    if (act) {
        const int wb = s ? 83 : -6;
        #pragma unroll
        for (int j = 0; j < NJ; ++j) {
            int q = r0 + j, w = wb + off + q;
            bool valid = (w >= 0) && (w < SEQ);
            #pragma unroll
            for (int u = 0; u < 8; ++u)
                in[q*CSTR + o0+u] = valid ? fmaxf(acc[j][u], 0.f) : 0.f;
        }
    }
    __syncthreads();
}

// ------------------------------------------------------------- step kernel
// grid 512, 256 threads. Block handles one batch x both edges (2 subs).
__launch_bounds__(256, 3)
__global__ void step_kernel(int i, const float* __restrict__ x_enc,
                            const int* __restrict__ y_mark,
                            const float* __restrict__ hour_e, const float* __restrict__ wk_e,
                            const float* __restrict__ day_e, const float* __restrict__ mon_e,
                            const float* __restrict__ W_val, const float* __restrict__ b_val,
                            const float* __restrict__ b1, const float* __restrict__ b2,
                            const float* __restrict__ b3, const float* __restrict__ gbi,
                            const float* __restrict__ out) {
    __shared__ float abuf[2*ASUB];     // 21.1 KB
    __shared__ float wbuf[16*GDIM];    // 24.6 KB (conv chunks use 5440 floats of it)
    const int tid = threadIdx.x;
    const int b = blockIdx.x;

    // ---- embedding: 2 subs x 20 rows x 128
    for (int e = tid; e < 2*20*DM; e += 256) {
        int s = e / (20*DM);
        int rem = e - s*(20*DM);
        int q = rem >> 7, d = rem & 127;
        int wb = s ? 83 : -6;
        int w = wb + q;
        float v = 0.f;
        if (w >= 0 && w < SEQ) {
            int p = i + w;
            const float* xr = (p < SEQ) ? (x_enc + (b*SEQ + p)*CIN)
                                        : (out + (b*PRED + (p - SEQ))*CIN);
            v = b_val[d];
            #pragma unroll
            for (int c = 0; c < CIN; ++c) v = fmaf(xr[c], W_val[d*CIN + c], v);
            const int* ym = y_mark + (b*TOT + p)*4;
            v += hour_e[ym[0]*DM + d] + wk_e[ym[1]*DM + d]
               + day_e[ym[2]*DM + d] + mon_e[ym[3]*DM + d];
        }
        abuf[s*ASUB + q*CSTR + d] = v;
    }
    mlayer<2>(abuf, wbuf, g_wT,            b1, 16, 2, tid);  // c1: 32 rows
    mlayer<2>(abuf, wbuf, g_wT + W_CONV,   b2, 12, 4, tid);  // c2: 24 rows
    mlayer<1>(abuf, wbuf, g_wT + 2*W_CONV, b3,  8, 6, tid);  // c3: 16 rows

    // ---- gx: 16 c3 rows; thread tile = 2 rows x 12 g
    const int mp = tid >> 5;                 // 0..7 row-pairs
    const int g0 = (tid & 31) * 12;
    const int s = mp >> 2;                   // sub-buffer
    const int row0 = (2*mp) & 7;
    const float* a0p = abuf + s*ASUB + row0*CSTR;
    const float* a1p = a0p + CSTR;
    const float* WiT = g_wT + OFF_WIT;
    float ga[2][12];
    #pragma unroll
    for (int e = 0; e < 12; ++e) { float bv = gbi[g0+e]; ga[0][e] = bv; ga[1][e] = bv; }
    for (int cc = 0; cc < 8; ++cc) {
        __syncthreads();
        for (int x = tid; x < 16*GDIM/4; x += 256)
            ((float4*)wbuf)[x] = ((const float4*)(WiT + cc*16*GDIM))[x];
        __syncthreads();
        #pragma unroll
        for (int c = 0; c < 16; ++c) {
            float av0 = a0p[cc*16 + c];
            float av1 = a1p[cc*16 + c];
            const float* wr = wbuf + c*GDIM + g0;
            #pragma unroll
            for (int q4 = 0; q4 < 3; ++q4) {
                float4 w4 = *(const float4*)(wr + q4*4);
                ga[0][q4*4+0] = fmaf(av0, w4.x, ga[0][q4*4+0]);
                ga[0][q4*4+1] = fmaf(av0, w4.y, ga[0][q4*4+1]);
                ga[0][q4*4+2] = fmaf(av0, w4.z, ga[0][q4*4+2]);
                ga[0][q4*4+3] = fmaf(av0, w4.w, ga[0][q4*4+3]);
                ga[1][q4*4+0] = fmaf(av1, w4.x, ga[1][q4*4+0]);
                ga[1][q4*4+1] = fmaf(av1, w4.y, ga[1][q4*4+1]);
                ga[1][q4*4+2] = fmaf(av1, w4.z, ga[1][q4*4+2]);
                ga[1][q4*4+3] = fmaf(av1, w4.w, ga[1][q4*4+3]);
            }
        }
    }
    const int wb = s ? 83 : -6;
    #pragma unroll
    for (int j = 0; j < 2; ++j) {
        int w = wb + 6 + row0 + j;
        float* dst = nullptr;
        if (s == 0) {
            if (w < 6) dst = g_gxe + ((size_t)b*12 + w)*GDIM + g0;
        } else {
            if (w == 89)      dst = g_gxg + ((size_t)b*TOT + (i + 89))*GDIM + g0;
            else if (w < SEQ) dst = g_gxe + ((size_t)b*12 + (w - 84))*GDIM + g0;
        }
        if (dst) {
            *(float4*)(dst)     = *(const float4*)&ga[j][0];
            *(float4*)(dst + 4) = *(const float4*)&ga[j][4];
            *(float4*)(dst + 8) = *(const float4*)&ga[j][8];
        }
    }
}

// -------------------------------------------------------------- recurrence v5
// grid 256 (NBB=2 batches/block), 512 threads = (unit j = tid>>2) x (c-slice
// s4 = tid&3). The 4 slice partials live in 4 adjacent lanes -> combine via
// __shfl_xor(1)+__shfl_xor(2): no P-LDS round trip, ONE barrier per t-step.
// Gate math runs redundantly in all 4 lanes; h(t-1) stays in a register.
__launch_bounds__(512, 2)
__global__ void gru_rec2(int i, const float* __restrict__ gbh,
                         const float* __restrict__ fc_w, const float* __restrict__ fc_b,
                         float* __restrict__ out) {
    __shared__ __align__(16) float H[2][NBB][144];   // ping-pong hidden, 36-padded
    const int tid = threadIdx.x;
    const int gj4 = tid >> 2, s4 = tid & 3;
    const int b0 = blockIdx.x * NBB;

    // Wh slice for (unit gj4, c in [32*s4, 32*s4+32)), all 3 gates (96 VGPRs)
    float whr[32], whz[32], whn[32];
    {
        const float* Wp = g_wT + OFF_WHT + (size_t)(32*s4)*GDIM + gj4;
        #pragma unroll
        for (int c = 0; c < 32; ++c) {
            whr[c] = Wp[c*GDIM];
            whz[c] = Wp[c*GDIM + DM];
            whn[c] = Wp[c*GDIM + 2*DM];
        }
    }
    const float bhr = gbh[gj4], bhz = gbh[DM + gj4], bhn = gbh[2*DM + gj4];

    for (int e = tid; e < 2*NBB*144; e += 512) ((float*)H)[e] = 0.f;

    const float* gxg_b0 = g_gxg + (size_t)b0*TOT*GDIM;
    const float* gxe_b0 = g_gxe + (size_t)b0*12*GDIM;
    auto gp = [&](int t, int bb) -> const float* {
        return (t < 6)  ? (gxe_b0 + (size_t)bb*12*GDIM + t*GDIM)
             : (t < 90) ? (gxg_b0 + (size_t)bb*TOT*GDIM + (size_t)(i + t)*GDIM)
                        : (gxe_b0 + (size_t)bb*12*GDIM + (t - 84)*GDIM);
    };

    float gxr[NBB], gxz[NBB], gxn[NBB], hold[NBB];
    #pragma unroll
    for (int bb = 0; bb < NBB; ++bb) {
        const float* g0p = gp(0, bb);
        gxr[bb] = g0p[gj4]; gxz[bb] = g0p[DM + gj4]; gxn[bb] = g0p[2*DM + gj4];
        hold[bb] = 0.f;
    }
    __syncthreads();

    for (int t = 0; t < SEQ; ++t) {
        // prefetch t+1's gx first: latency hides under the dots below
        float nr[NBB], nz[NBB], nn[NBB];
        #pragma unroll
        for (int bb = 0; bb < NBB; ++bb) { nr[bb] = nz[bb] = nn[bb] = 0.f; }
        if (t + 1 < SEQ) {
            #pragma unroll
            for (int bb = 0; bb < NBB; ++bb) {
                const float* gq = gp(t + 1, bb);
                nr[bb] = gq[gj4]; nz[bb] = gq[DM + gj4]; nn[bb] = gq[2*DM + gj4];
            }
        }
        #pragma unroll
        for (int bb = 0; bb < NBB; ++bb) {
            // 36-pad -> the 4 slices' float4 reads hit disjoint bank groups
            const float* Hc = &H[t & 1][bb][36*s4];
            float ar = 0.f, az = 0.f, an = 0.f;
            #pragma unroll
            for (int c = 0; c < 32; c += 4) {
                float4 h4 = *(const float4*)(Hc + c);
                ar = fmaf(h4.x, whr[c],   ar); az = fmaf(h4.x, whz[c],   az); an = fmaf(h4.x, whn[c],   an);
                ar = fmaf(h4.y, whr[c+1], ar); az = fmaf(h4.y, whz[c+1], az); an = fmaf(h4.y, whn[c+1], an);
                ar = fmaf(h4.z, whr[c+2], ar); az = fmaf(h4.z, whz[c+2], az); an = fmaf(h4.z, whn[c+2], an);
                ar = fmaf(h4.w, whr[c+3], ar); az = fmaf(h4.w, whz[c+3], az); an = fmaf(h4.w, whn[c+3], an);
            }
            // combine the 4 slice lanes (lane group tid>>2)
            ar += __shfl_xor(ar, 1); ar += __shfl_xor(ar, 2);
            az += __shfl_xor(az, 1); az += __shfl_xor(az, 2);
            an += __shfl_xor(an, 1); an += __shfl_xor(an, 2);
            // gate math (redundant in the 4 lanes)
            float r = 1.f/(1.f + __expf(-(gxr[bb] + bhr + ar)));
            float z = 1.f/(1.f + __expf(-(gxz[bb] + bhz + az)));
            float xn = gxn[bb] + r*(bhn + an);
            float e2 = __expf(2.f*xn);
            float n = 1.f - 2.f/(e2 + 1.f);            // tanh(xn)
            float h = (1.f - z)*n + z*hold[bb];
            hold[bb] = h;
            if (s4 == 0)
                H[(t + 1) & 1][bb][36*(gj4 >> 5) + (gj4 & 31)] = h;
            gxr[bb] = nr[bb]; gxz[bb] = nz[bb]; gxn[bb] = nn[bb];
        }
        __syncthreads();                               // h visible for next t
    }

    // ---- pred = h @ fc_w^T + fc_b (SEQ even -> final state in H[0])
    if (tid < NBB*CIN) {
        int bb = tid / CIN, o = tid % CIN;
        float p = fc_b[o];
        #pragma unroll
        for (int d = 0; d < DM; ++d)
            p = fmaf(fc_w[o*DM + d], H[0][bb][36*(d >> 5) + (d & 31)], p);
        out[((b0 + bb)*PRED + i)*CIN + o] = p;
    }
}

// ---------------------------------------------------------------- launch
extern "C" void kernel_launch(void* const* d_in, const int* in_sizes, int n_in,
                              void* d_out, int out_size, void* d_ws, size_t ws_size,
                              hipStream_t stream) {
    const float* x_enc  = (const float*)d_in[0];
    const int*   y_mark = (const int*)d_in[2];
    const float* hour_e = (const float*)d_in[3];
    const float* wk_e   = (const float*)d_in[4];
    const float* day_e  = (const float*)d_in[5];
    const float* mon_e  = (const float*)d_in[6];
    const float* W_val  = (const float*)d_in[7];
    const float* b_val  = (const float*)d_in[8];
    const float* c1w    = (const float*)d_in[9];
    const float* c1b    = (const float*)d_in[10];
    const float* c2w    = (const float*)d_in[11];
    const float* c2b    = (const float*)d_in[12];
    const float* c3w    = (const float*)d_in[13];
    const float* c3b    = (const float*)d_in[14];
    const float* Wi     = (const float*)d_in[15];
    const float* Wh     = (const float*)d_in[16];
    const float* gbi    = (const float*)d_in[17];
    const float* gbh    = (const float*)d_in[18];
    const float* fcw    = (const float*)d_in[19];
    const float* fcb    = (const float*)d_in[20];
    float* out = (float*)d_out;

    prep_weights<<<(W_TOTAL + 255)/256, 256, 0, stream>>>(c1w, c2w, c3w, Wi, Wh);

    init_kernel<<<dim3(B_SZ, 2), 256, 0, stream>>>(x_enc, y_mark,
        hour_e, wk_e, day_e, mon_e, W_val, b_val, c1b, c2b, c3b, gbi);

    for (int i = 0; i < PRED; ++i) {
        step_kernel<<<B_SZ, 256, 0, stream>>>(i, x_enc, y_mark,
            hour_e, wk_e, day_e, mon_e, W_val, b_val, c1b, c2b, c3b, gbi, out);
        gru_rec2<<<B_SZ/NBB, 512, 0, stream>>>(i, gbh, fcw, fcb, out);
    }
}